// Round 6
// baseline (644.712 us; speedup 1.0000x reference)
//
#include <hip/hip_runtime.h>
#include <stdint.h>
#include <stddef.h>

static constexpr int MM   = 2000;   // sites
static constexpr int NN   = 1000;   // states
static constexpr int NB2  = 32;     // 2B haplotype rows
static constexpr int DDIM = 5000;   // gexp dim
static constexpr int NPR  = 1008;   // F/S row stride in elements
static constexpr int NG   = 500;    // MM/4 groups
static constexpr int JB   = 8;      // batch size (sites per exchange)
static constexpr int NBAT = MM/JB;  // 250 batches per chain
static constexpr int NCR  = 36;     // C-record floats per batch (J*(J+1)/2)
static constexpr float EAV = 0.991f; // (1-0.01) + 1/1000
static constexpr float EBV = 0.011f; // 0.01 + 1/1000

typedef uint32_t u32x4 __attribute__((ext_vector_type(4)));
typedef uint32_t u32x2 __attribute__((ext_vector_type(2)));
typedef float    f32x2 __attribute__((ext_vector_type(2)));

__device__ __forceinline__ float rcp_fast(float x){ return __builtin_amdgcn_rcpf(x); }

// LDS-only barrier: orders ds_write -> ds_read across waves WITHOUT draining
// vmcnt (global loads/stores stay in flight across batches).
__device__ __forceinline__ void barrier_lds_only(){
  __builtin_amdgcn_sched_barrier(0);
  asm volatile("s_waitcnt lgkmcnt(0)" ::: "memory");
  __builtin_amdgcn_s_barrier();
  __builtin_amdgcn_sched_barrier(0);
}

// Two independent full-wave sums, DPP stages interleaved (k_sites).
__device__ __forceinline__ void wave_total2(float &a, float &b){
  int xa, xb;
  xa = __builtin_amdgcn_update_dpp(0, __float_as_int(a), 0x111, 0xf, 0xf, true);
  xb = __builtin_amdgcn_update_dpp(0, __float_as_int(b), 0x111, 0xf, 0xf, true);
  a += __int_as_float(xa); b += __int_as_float(xb);
  xa = __builtin_amdgcn_update_dpp(0, __float_as_int(a), 0x112, 0xf, 0xf, true);
  xb = __builtin_amdgcn_update_dpp(0, __float_as_int(b), 0x112, 0xf, 0xf, true);
  a += __int_as_float(xa); b += __int_as_float(xb);
  xa = __builtin_amdgcn_update_dpp(0, __float_as_int(a), 0x114, 0xf, 0xf, true);
  xb = __builtin_amdgcn_update_dpp(0, __float_as_int(b), 0x114, 0xf, 0xf, true);
  a += __int_as_float(xa); b += __int_as_float(xb);
  xa = __builtin_amdgcn_update_dpp(0, __float_as_int(a), 0x118, 0xf, 0xf, true);
  xb = __builtin_amdgcn_update_dpp(0, __float_as_int(b), 0x118, 0xf, 0xf, true);
  a += __int_as_float(xa); b += __int_as_float(xb);
  xa = __builtin_amdgcn_update_dpp(0, __float_as_int(a), 0x142, 0xa, 0xf, false);
  xb = __builtin_amdgcn_update_dpp(0, __float_as_int(b), 0x142, 0xa, 0xf, false);
  a += __int_as_float(xa); b += __int_as_float(xb);
  xa = __builtin_amdgcn_update_dpp(0, __float_as_int(a), 0x143, 0xc, 0xf, false);
  xb = __builtin_amdgcn_update_dpp(0, __float_as_int(b), 0x143, 0xc, 0xf, false);
  a += __int_as_float(xa); b += __int_as_float(xb);
  a = __int_as_float(__builtin_amdgcn_readlane(__float_as_int(a), 63));
  b = __int_as_float(__builtin_amdgcn_readlane(__float_as_int(b), 63));
}

// 8 interleaved full-wave sums; totals valid in lane 63.
template<int C,int RM,int BM,bool BC>
__device__ __forceinline__ void dpp_stage8(float m[8]){
  int x[8];
  #pragma unroll
  for (int j = 0; j < 8; ++j)
    x[j] = __builtin_amdgcn_update_dpp(0, __float_as_int(m[j]), C, RM, BM, BC);
  #pragma unroll
  for (int j = 0; j < 8; ++j) m[j] += __int_as_float(x[j]);
}
__device__ __forceinline__ void wave_total8_63(float m[8]){
  dpp_stage8<0x111,0xf,0xf,true>(m);
  dpp_stage8<0x112,0xf,0xf,true>(m);
  dpp_stage8<0x114,0xf,0xf,true>(m);
  dpp_stage8<0x118,0xf,0xf,true>(m);
  dpp_stage8<0x142,0xa,0xf,false>(m);
  dpp_stage8<0x143,0xc,0xf,false>(m);
}

// static-index accessor for a float4[9] record (avoids scratch; indices fold)
#define CCEL(A,i) ( ((i)&3)==0 ? (A)[(i)>>2].x : ((i)&3)==1 ? (A)[(i)>>2].y : \
                    ((i)&3)==2 ? (A)[(i)>>2].z : (A)[(i)>>2].w )

// ---------------- K0: pack ref bits + ref bytes -----
__global__ __launch_bounds__(64) void k_pack(const int* __restrict__ ref,
                                             uint64_t* __restrict__ pack,
                                             uint4* __restrict__ refB4){
  int g = blockIdx.x;
  int t = threadIdx.x;   // lane
  uint64_t wv = 0;
  for (int c = 0; c < 4; ++c){
    int i = g*4 + c;
    uint32_t m16 = 0;
    uint32_t d[4] = {0,0,0,0};
    #pragma unroll
    for (int j = 0; j < 16; ++j){
      int k = t*16 + j;
      uint32_t v = (k < NN) ? (uint32_t)(ref[(size_t)i*NN + k] & 1) : 0u;
      m16 |= v << j;
      d[j>>2] |= v << (8*(j&3));
    }
    wv |= (uint64_t)m16 << (16*c);
    refB4[(size_t)i*64 + t] = make_uint4(d[0],d[1],d[2],d[3]);
  }
  pack[(size_t)g*64 + t] = wv;
}

// ---------------- K0a: obs bit words (parallel) -----
__global__ __launch_bounds__(64) void k_obs(const float* __restrict__ xoh,
                                            uint32_t* __restrict__ obsw){
  int b2 = blockIdx.x;
  int w  = threadIdx.x;      // word index 0..63
  uint32_t word = 0;
  int base = w*32;
  #pragma unroll 4
  for (int z = 0; z < 32; ++z){
    int i = base + z;
    if (i < MM){
      float x1 = xoh[(size_t)b2*MM*2 + (size_t)i*2 + 1];
      if (x1 > 0.5f) word |= 1u << z;
    }
  }
  obsw[b2*64 + w] = word;
}

// ---------------- K0b: forward scalar table (c0,c1,1-rn,rn/n) -----
__global__ __launch_bounds__(256) void k_prep2(const float* __restrict__ xoh,
                                               const float* __restrict__ recomb,
                                               float4* __restrict__ FC4){
  int idx = blockIdx.x*256 + threadIdx.x;
  if (idx < NB2*MM){
    int b2 = idx / MM, i = idx - b2*MM;
    float x1 = xoh[(size_t)b2*MM*2 + (size_t)i*2 + 1];
    bool obs = x1 > 0.5f;
    float c0 = obs ? EBV : EAV;
    float c1 = obs ? (EAV-EBV) : (EBV-EAV);
    float rn = (i+1 < MM) ? recomb[i+1] : 0.5f;
    FC4[(size_t)b2*MM + i] = make_float4(c0, c1, 1.0f - rn, rn/(float)NN);
  }
}

// ---------------- K1: GEMM partial ----------------
__global__ __launch_bounds__(256) void k_gemm(const float* __restrict__ gexp,
                                              const float* __restrict__ W,
                                              float* __restrict__ part){
  int cb = blockIdx.x;        // 0..7 column block
  int c  = blockIdx.y;        // 0..15 d-chunk
  int t  = threadIdx.x;
  int d0 = (c*DDIM) >> 4, d1 = ((c+1)*DDIM) >> 4;
  int len = d1 - d0;          // 312 or 313
  __shared__ __align__(16) float lg[313*20];
  for (int bb = 0; bb < 16; ++bb)
    for (int dd = t; dd < len; dd += 256)
      lg[dd*20 + bb] = gexp[(size_t)bb*DDIM + d0 + dd];
  __syncthreads();
  int i = cb*256 + t;
  if (i < MM){
    float acc[16];
    #pragma unroll
    for (int bb = 0; bb < 16; ++bb) acc[bb] = 0.f;
    for (int dd = 0; dd < len; ++dd){
      float w = W[(size_t)(d0 + dd)*MM + i];
      const float4* lp = (const float4*)&lg[dd*20];
      float4 g0 = lp[0], g1 = lp[1], g2 = lp[2], g3 = lp[3];
      acc[0]  += g0.x*w; acc[1]  += g0.y*w; acc[2]  += g0.z*w; acc[3]  += g0.w*w;
      acc[4]  += g1.x*w; acc[5]  += g1.y*w; acc[6]  += g1.z*w; acc[7]  += g1.w*w;
      acc[8]  += g2.x*w; acc[9]  += g2.y*w; acc[10] += g2.z*w; acc[11] += g2.w*w;
      acc[12] += g3.x*w; acc[13] += g3.y*w; acc[14] += g3.z*w; acc[15] += g3.w*w;
    }
    #pragma unroll
    for (int bb = 0; bb < 16; ++bb)
      part[((size_t)c*16 + bb)*MM + i] = acc[bb];
  }
}

// ---------------- K2: reduce partials -> logits; backward scalar table -----
__global__ __launch_bounds__(256) void k_gemmreduce(const float* __restrict__ part,
                                                    const float* __restrict__ bias,
                                                    const float* __restrict__ recomb,
                                                    float* __restrict__ acc,
                                                    float4* __restrict__ BC4){
  int idx = blockIdx.x*256 + threadIdx.x;
  if (idx < 16*MM){
    float s = 0.f;
    #pragma unroll
    for (int c = 0; c < 16; ++c) s += part[(size_t)c*16*MM + idx];
    acc[idx] = s;
    int bb = idx / MM, i = idx - bb*MM;
    float z = s + bias[i];
    float p = rcp_fast(1.0f + __expf(-z));
    float v0 = EAV + (EBV-EAV)*p;
    float v1 = EBV + (EAV-EBV)*p;
    float r = recomb[i];
    BC4[idx] = make_float4(v0, v1 - v0, 1.0f - r, r/(float)NN);
  }
}

// ---------------- K2b: per-batch emission-product sums C_{l,j} ----------
__global__ __launch_bounds__(64) void k_ctab(const uint4* __restrict__ refB4,
                                             const float4* __restrict__ FC4,
                                             const float4* __restrict__ BC4,
                                             float* __restrict__ Cout){
  int wid  = blockIdx.x;           // 0 .. 64*NBAT-1
  int lane = threadIdx.x;
  int chain = wid / NBAT;
  int nb    = wid - chain*NBAT;
  int DIR = (chain < 32) ? 1 : -1;
  int b2  = chain & 31;
  const float4* ctab = (chain < 32) ? (FC4 + (size_t)b2*MM) : (BC4 + (size_t)(b2>>1)*MM);
  int start = (DIR > 0) ? 0 : (MM-1);

  // build e for the batch's 8 sites (16 states/lane)
  f32x2 e[8][8];
  #pragma unroll
  for (int m = 0; m < 8; ++m){
    int site = start + DIR*(nb*JB + m);
    uint4 by = refB4[(size_t)site*64 + lane];
    float4 cc = ctab[site];
    f32x2 c0p; c0p.x = cc.x; c0p.y = cc.x;
    f32x2 c1p; c1p.x = cc.y; c1p.y = cc.y;
    uint32_t rw[4] = {by.x, by.y, by.z, by.w};
    #pragma unroll
    for (int q = 0; q < 4; ++q){
      f32x2 b01, b23;
      b01.x = (float)( rw[q]        & 0xFFu);
      b01.y = (float)((rw[q] >> 8)  & 0xFFu);
      b23.x = (float)((rw[q] >> 16) & 0xFFu);
      b23.y = (float)( rw[q] >> 24);
      e[m][2*q]   = c0p + c1p*b01;
      e[m][2*q+1] = c0p + c1p*b23;
    }
  }
  const float mlo = (lane < 63) ? 1.0f : 0.0f;  // pairs 0..3 (states +0..7)
  const float mhi = (lane < 62) ? 1.0f : 0.0f;  // pairs 4..7 (states +8..15)

  __shared__ float red[64*NCR];
  int cnt = 0;
  #pragma unroll
  for (int l = 0; l < 8; ++l){
    f32x2 c[8];
    #pragma unroll
    for (int q = 0; q < 8; ++q){
      f32x2 mk; mk.x = (q < 4) ? mlo : mhi; mk.y = mk.x;
      c[q] = e[l][q] * mk;
    }
    #pragma unroll
    for (int jj = l; jj < 8; ++jj){
      if (jj > l){
        #pragma unroll
        for (int q = 0; q < 8; ++q) c[q] = c[q] * e[jj][q];
      }
      f32x2 s0 = (c[0]+c[1]) + (c[2]+c[3]);
      f32x2 s1 = (c[4]+c[5]) + (c[6]+c[7]);
      f32x2 ss = s0 + s1;
      red[lane*NCR + cnt] = ss.x + ss.y;
      ++cnt;
    }
  }
  __syncthreads();
  if (lane < NCR){
    float s = 0.f;
    #pragma unroll
    for (int k = 0; k < 64; ++k) s += red[k*NCR + lane];
    Cout[(size_t)wid*NCR + lane] = s;
  }
}

// ---------------- K3: sequential chains, batched exchange (J=8), 8 waves ------
// Round-6 change: 8 waves per chain (512 threads), 2 states/lane.
// Rationale: R5 showed ~80% SIMD stall with 1 wave/SIMD (issue ~560cy of
// 2765cy/batch). 2 waves/SIMD fill each other's stall slots. Elementwise
// work halves per wave; DPP/scalar skeleton is per-wave constant.
// Also: deferred stores (packed into vst[8], issued after j-loop — removes
// mid-chain vmcnt register-reuse waits) and lane-indexed exchange read
// (2 ds_read_b128 + in-lane sum + 8 readlane instead of 8 uniform reads).
template<int DIR>
__device__ void run_chain8(const uint16_t* __restrict__ refH,
                           const float4* __restrict__ ctab,
                           const float* __restrict__ Crec,
                           uint16_t* __restrict__ outp,
                           int b2, int w, int lane,
                           float4* lds_ctab, float* lds_C, float* partb){
  int tid = w*64 + lane;
  for (int idx = tid; idx < MM; idx += 512) lds_ctab[idx] = ctab[idx];
  for (int idx = tid; idx < NBAT*NCR; idx += 512) lds_C[idx] = Crec[idx];
  __syncthreads();

  const int st0 = w*128 + lane*2;                 // first state of this lane
  const float mv  = (st0 < NN)  ? 1.0f : 0.0f;    // NN even: pair never split
  const bool doSt = (st0 < NPR);                  // states < 1008 stored

  const ptrdiff_t rstep = (ptrdiff_t)DIR * 512;   // ushorts per site
  const uint16_t* rp = refH + ((DIR > 0) ? 0 : (ptrdiff_t)(MM-1)*512) + tid;
  const ptrdiff_t ostep = (ptrdiff_t)DIR * NB2 * NPR;  // uint16 units per site
  uint16_t* op = outp + (size_t)b2*NPR
               + ((DIR > 0) ? (size_t)0 : (size_t)(MM-1)*(size_t)NB2*NPR)
               + (size_t)st0;

  uint32_t A[8], Bv[8];
  #pragma unroll
  for (int k = 0; k < 8; ++k) A[k]  = rp[(ptrdiff_t)k*rstep];
  #pragma unroll
  for (int k = 0; k < 8; ++k) Bv[k] = rp[(ptrdiff_t)(k+8)*rstep];

  int ci = (DIR > 0) ? 0 : (MM-1);

  float4 cur8[8];
  #pragma unroll
  for (int k = 0; k < 8; ++k) cur8[k] = lds_ctab[ci + DIR*k];

  f32x2 g; g.x = 0.f; g.y = 0.f;
  float dd      = 1.0f/(float)NN;  // d_{i0-1}
  float az_prev = 0.0f;            // az_{i0-1}
  int buf = 0;
  constexpr int CO[8] = {0,8,15,21,26,30,33,35};

  #pragma unroll 2
  for (int n = 0; n < NBAT; ++n){
    // ---- prefetch ref bytes two batches ahead (global; stays in flight) ----
    uint32_t Cv[8];
    #pragma unroll
    for (int k = 0; k < 8; ++k) Cv[k] = rp[(ptrdiff_t)(8*n + 16 + k)*rstep];
    // ---- prefetch next batch's per-site scalars (LDS; consumed next iter) ----
    float4 nx8[8];
    {
      int cin = (n < NBAT-1) ? (ci + DIR*8) : ci;
      #pragma unroll
      for (int k = 0; k < 8; ++k) nx8[k] = lds_ctab[cin + DIR*k];
    }
    // ---- this batch's C record (LDS; consumed post-barrier) ----
    float4 CC[9];
    {
      const float4* crp = (const float4*)(lds_C + n*NCR);
      #pragma unroll
      for (int r = 0; r < 9; ++r) CC[r] = crp[r];
    }
    // ---- build e for the batch ----
    f32x2 e[8];
    #pragma unroll
    for (int k = 0; k < 8; ++k){
      uint32_t rw = A[k];
      f32x2 b01;
      b01.x = (float)( rw        & 0xFFu);
      b01.y = (float)( rw >> 8);
      f32x2 c0p; c0p.x = cur8[k].x; c0p.y = cur8[k].x;
      f32x2 c1p; c1p.x = cur8[k].y; c1p.y = cur8[k].y;
      e[k] = c0p + c1p*b01;
    }
    // ---- cumprod moments ----
    float m[8];
    {
      f32x2 c = g*e[0];
      m[0] = c.x + c.y;
      #pragma unroll
      for (int k = 1; k < 8; ++k){
        c = c*e[k];
        m[k] = c.x + c.y;
      }
    }
    wave_total8_63(m);
    if (lane == 63){
      #pragma unroll
      for (int j = 0; j < 8; ++j) partb[buf*64 + j*8 + w] = m[j];
    }
    barrier_lds_only();
    // lane-indexed read: lane l sums partb[buf][l&7][0..7]; readlane -> M[j]
    float M[8];
    {
      int ll = lane & 7;
      const float4* pb = (const float4*)(partb + buf*64 + ll*8);
      float4 pa = pb[0], pc = pb[1];
      float msum = ((pa.x+pa.y)+(pa.z+pa.w)) + ((pc.x+pc.y)+(pc.z+pc.w));
      #pragma unroll
      for (int j = 0; j < 8; ++j)
        M[j] = __int_as_float(__builtin_amdgcn_readlane(__float_as_int(msum), j));
    }
    // ---- fused scalar recurrence + elementwise evolve; stores deferred ----
    uint32_t vst[8];
    float cf[8];
    float azp = az_prev;
    float R = 1.0f;
    #pragma unroll
    for (int j = 0; j < 8; ++j){
      if (j > 0){
        float azm = cur8[j-1].z;
        azp *= azm;
        #pragma unroll
        for (int l = 0; l < 8; ++l) if (l < j) cf[l] *= azm;
      }
      cf[j] = dd;
      float az_j = (j == 0) ? az_prev : cur8[j-1].z;
      float dm = dd * mv;
      f32x2 azv; azv.x = az_j; azv.y = az_j;
      f32x2 dmv; dmv.x = dm;   dmv.y = dm;
      f32x2 t = g*azv + dmv;
      vst[j] = __builtin_amdgcn_perm(__float_as_uint(t.y), __float_as_uint(t.x), 0x07060302u);
      g = t*e[j];
      float T = azp * M[j];
      #pragma unroll
      for (int l = 0; l < 8; ++l) if (l <= j) T = fmaf(cf[l], CCEL(CC, CO[l] + (j-l)), T);
      R = T;
      dd = cur8[j].w * R;
    }
    // ---- deferred stores (one dword per site) ----
    if (doSt){
      uint16_t* o = op;
      #pragma unroll
      for (int j = 0; j < 8; ++j){
        *(uint32_t*)o = vst[j];
        o += ostep;
      }
    }
    op += 8*ostep;
    // ---- per-batch renorm (range only; scale cancels downstream) ----
    float s = rcp_fast(R);
    f32x2 sp; sp.x = s; sp.y = s;
    g = g*sp;
    dd *= s;
    az_prev = cur8[7].z;
    ci += DIR*8;
    buf ^= 1;
    #pragma unroll
    for (int k = 0; k < 8; ++k){ A[k] = Bv[k]; Bv[k] = Cv[k]; }
    #pragma unroll
    for (int k = 0; k < 8; ++k) cur8[k] = nx8[k];
  }
}

__global__ __launch_bounds__(512, 1) void k_chains(const uint4* __restrict__ refB4,
                                                   const float4* __restrict__ FC4,
                                                   const float4* __restrict__ BC4,
                                                   const float* __restrict__ Cw,
                                                   uint16_t* __restrict__ F,
                                                   uint16_t* __restrict__ S){
  __shared__ __align__(16) float4 lds_ctab[MM];
  __shared__ __align__(16) float lds_C[NBAT*NCR];
  __shared__ __align__(16) float partb[128];   // [2 buf][8 j][8 w]
  int lane = threadIdx.x & 63;
  int w    = threadIdx.x >> 6;
  int blk  = blockIdx.x;
  int b2   = blk & 31;
  const uint16_t* refH = (const uint16_t*)refB4;
  const float* Crec = Cw + (size_t)blk*NBAT*NCR;
  if (blk < 32) run_chain8<1>(refH, FC4 + (size_t)b2*MM, Crec, F, b2, w, lane,
                              lds_ctab, lds_C, partb);
  else          run_chain8<-1>(refH, BC4 + (size_t)(b2>>1)*MM, Crec, S, b2, w, lane,
                               lds_ctab, lds_C, partb);
}

// ---------------- K4: per-site p_xe terms (fully parallel). wave per (i,b2). ----------
__global__ __launch_bounds__(256) void k_sites(const uint16_t* __restrict__ F,
                                               const uint16_t* __restrict__ S,
                                               const uint64_t* __restrict__ pack,
                                               const uint32_t* __restrict__ obsw,
                                               const float* __restrict__ acc,
                                               const float* __restrict__ bias,
                                               float* __restrict__ terms){
  int lane = threadIdx.x & 63;
  int wid  = threadIdx.x >> 6;
  int s    = blockIdx.x*4 + wid;     // 0 .. 63999
  int i    = s >> 5;
  int b2   = s & 31;
  uint4 f0 = make_uint4(0,0,0,0), f1 = f0, s0 = f0, s1 = f0;
  if (lane < 63){
    size_t off = ((size_t)i*NB2 + b2)*NPR + lane*16;
    const uint4* fp = (const uint4*)(F + off);
    const uint4* sp = (const uint4*)(S + off);
    f0 = fp[0]; f1 = fp[1];
    s0 = sp[0]; s1 = sp[1];
  }
  uint32_t m16 = (uint32_t)(pack[(size_t)(i>>2)*64 + lane] >> (16*(i&3))) & 0xFFFFu;

  uint32_t fa[8] = {f0.x,f0.y,f0.z,f0.w,f1.x,f1.y,f1.z,f1.w};
  uint32_t sa[8] = {s0.x,s0.y,s0.z,s0.w,s1.x,s1.y,s1.z,s1.w};
  float Tt = 0.f, Tb = 0.f;
  #pragma unroll
  for (int q = 0; q < 8; ++q){
    float flo = __uint_as_float(fa[q] << 16);
    float fhi = __uint_as_float(fa[q] & 0xFFFF0000u);
    float slo = __uint_as_float(sa[q] << 16);
    float shi = __uint_as_float(sa[q] & 0xFFFF0000u);
    float pl = flo*slo, ph = fhi*shi;
    Tt += pl + ph;
    Tb += (((m16 >> (2*q)) & 1u) ? pl : 0.f) + (((m16 >> (2*q+1)) & 1u) ? ph : 0.f);
  }
  wave_total2(Tt, Tb);
  if (lane == 0){
    uint32_t obsb = (obsw[b2*64 + (i>>5)] >> (i & 31)) & 1u;
    float z = acc[(size_t)(b2 >> 1)*MM + i] + bias[i];
    float p = rcp_fast(1.0f + __expf(-z));
    float A = Tt - Tb, B = Tb;
    float d0 = EAV*A + EBV*B;
    float d1 = EBV*A + EAV*B;
    float w0 = d0*(1.0f - p), w1 = d1*p;
    float term = __logf((obsb ? w1 : w0) * rcp_fast(w0 + w1));
    terms[s] = term;
  }
}

// ---------------- K5: final reduction ----------
__global__ __launch_bounds__(256) void k_final(const float* __restrict__ terms,
                                               float* __restrict__ out){
  __shared__ float red[256];
  float s = 0.f;
  for (int idx = threadIdx.x; idx < MM*NB2; idx += 256) s += terms[idx];
  red[threadIdx.x] = s;
  __syncthreads();
  for (int st = 128; st > 0; st >>= 1){
    if (threadIdx.x < st) red[threadIdx.x] += red[threadIdx.x + st];
    __syncthreads();
  }
  if (threadIdx.x == 0) out[0] = -red[0];
}

extern "C" void kernel_launch(void* const* d_in, const int* in_sizes, int n_in,
                              void* d_out, int out_size, void* d_ws, size_t ws_size,
                              hipStream_t stream){
  const float* gexp   = (const float*)d_in[0];   // [16,5000]
  const float* xoh    = (const float*)d_in[1];   // [32,2000,2]
  const float* W      = (const float*)d_in[2];   // [5000,2000]
  const float* bias   = (const float*)d_in[3];   // [2000]
  const int*   ref    = (const int*)d_in[4];     // [2000,1000]
  const float* recomb = (const float*)d_in[5];   // [2000]
  float* out = (float*)d_out;
  char* ws = (char*)d_ws;

  const size_t stateBytes = (size_t)MM*NB2*NPR*2;      // 129,024,000 per array (bf16)
  size_t offF    = 0;
  size_t offS    = offF + stateBytes;                  // 129,024,000
  size_t offPack = offS + stateBytes;                  // 258,048,000
  size_t offObs  = offPack + (size_t)NG*64*8;          // 258,304,000
  size_t offPart = offObs + 32*64*4;                   // 258,312,192 (2,048,000)
  size_t offTerm = offPart + (size_t)16*16*MM*4;       // 260,360,192 (256,000)
  size_t offAcc  = offTerm + (size_t)MM*NB2*4;         // 260,616,192 (128,000)
  size_t offRefB = offAcc + (size_t)16*MM*4;           // 260,744,192
  size_t offFC4  = offRefB + (size_t)(MM+32)*1024;     // 262,824,960
  size_t offBC4  = offFC4 + (size_t)NB2*MM*16;         // 263,848,960 (+512,000)

  uint16_t* Fb   = (uint16_t*)(ws + offF);
  uint16_t* Sb   = (uint16_t*)(ws + offS);
  uint64_t* pack = (uint64_t*)(ws + offPack);
  uint32_t* obsw = (uint32_t*)(ws + offObs);
  float*    part = (float*)(ws + offPart);
  float*    Cw   = (float*)(ws + offPart);             // aliases part+term
  float*    term = (float*)(ws + offTerm);
  float*    accp = (float*)(ws + offAcc);
  uint4*    refB = (uint4*)(ws + offRefB) + 16*64;     // site 0, pad +/-16 sites
  float4*   FC4  = (float4*)(ws + offFC4);
  float4*   BC4  = (float4*)(ws + offBC4);

  hipLaunchKernelGGL(k_pack, dim3(NG), dim3(64), 0, stream, ref, pack, refB);
  hipLaunchKernelGGL(k_obs, dim3(32), dim3(64), 0, stream, xoh, obsw);
  hipLaunchKernelGGL(k_prep2, dim3((NB2*MM+255)/256), dim3(256), 0, stream, xoh, recomb, FC4);
  hipLaunchKernelGGL(k_gemm, dim3(8,16), dim3(256), 0, stream, gexp, W, part);
  hipLaunchKernelGGL(k_gemmreduce, dim3(125), dim3(256), 0, stream, part, bias, recomb, accp, BC4);
  hipLaunchKernelGGL(k_ctab, dim3(64*NBAT), dim3(64), 0, stream, refB, FC4, BC4, Cw);
  hipLaunchKernelGGL(k_chains, dim3(64), dim3(512), 0, stream, refB, FC4, BC4, Cw, Fb, Sb);
  hipLaunchKernelGGL(k_sites, dim3(MM*NB2/4), dim3(256), 0, stream, Fb, Sb, pack, obsw, accp, bias, term);
  hipLaunchKernelGGL(k_final, dim3(1), dim3(256), 0, stream, term, out);
}

// Round 7
// 609.813 us; speedup vs baseline: 1.0572x; 1.0572x over previous
//
#include <hip/hip_runtime.h>
#include <stdint.h>
#include <stddef.h>

static constexpr int MM   = 2000;   // sites
static constexpr int NN   = 1000;   // states
static constexpr int NB2  = 32;     // 2B haplotype rows
static constexpr int DDIM = 5000;   // gexp dim
static constexpr int NPR  = 1008;   // F/S row stride in elements
static constexpr int NG   = 500;    // MM/4 groups
static constexpr int JB   = 8;      // batch size (sites per exchange)
static constexpr int NBAT = MM/JB;  // 250 batches per chain
static constexpr int NCR  = 36;     // C-record floats per batch (J*(J+1)/2)
static constexpr float EAV = 0.991f; // (1-0.01) + 1/1000
static constexpr float EBV = 0.011f; // 0.01 + 1/1000

typedef uint32_t u32x4 __attribute__((ext_vector_type(4)));
typedef uint32_t u32x2 __attribute__((ext_vector_type(2)));
typedef float    f32x2 __attribute__((ext_vector_type(2)));

__device__ __forceinline__ float rcp_fast(float x){ return __builtin_amdgcn_rcpf(x); }

// LDS-only barrier: orders ds_write -> ds_read across waves WITHOUT draining
// vmcnt (global loads/stores stay in flight across batches).
__device__ __forceinline__ void barrier_lds_only(){
  __builtin_amdgcn_sched_barrier(0);
  asm volatile("s_waitcnt lgkmcnt(0)" ::: "memory");
  __builtin_amdgcn_s_barrier();
  __builtin_amdgcn_sched_barrier(0);
}

// Two independent full-wave sums, DPP stages interleaved (k_sites).
__device__ __forceinline__ void wave_total2(float &a, float &b){
  int xa, xb;
  xa = __builtin_amdgcn_update_dpp(0, __float_as_int(a), 0x111, 0xf, 0xf, true);
  xb = __builtin_amdgcn_update_dpp(0, __float_as_int(b), 0x111, 0xf, 0xf, true);
  a += __int_as_float(xa); b += __int_as_float(xb);
  xa = __builtin_amdgcn_update_dpp(0, __float_as_int(a), 0x112, 0xf, 0xf, true);
  xb = __builtin_amdgcn_update_dpp(0, __float_as_int(b), 0x112, 0xf, 0xf, true);
  a += __int_as_float(xa); b += __int_as_float(xb);
  xa = __builtin_amdgcn_update_dpp(0, __float_as_int(a), 0x114, 0xf, 0xf, true);
  xb = __builtin_amdgcn_update_dpp(0, __float_as_int(b), 0x114, 0xf, 0xf, true);
  a += __int_as_float(xa); b += __int_as_float(xb);
  xa = __builtin_amdgcn_update_dpp(0, __float_as_int(a), 0x118, 0xf, 0xf, true);
  xb = __builtin_amdgcn_update_dpp(0, __float_as_int(b), 0x118, 0xf, 0xf, true);
  a += __int_as_float(xa); b += __int_as_float(xb);
  xa = __builtin_amdgcn_update_dpp(0, __float_as_int(a), 0x142, 0xa, 0xf, false);
  xb = __builtin_amdgcn_update_dpp(0, __float_as_int(b), 0x142, 0xa, 0xf, false);
  a += __int_as_float(xa); b += __int_as_float(xb);
  xa = __builtin_amdgcn_update_dpp(0, __float_as_int(a), 0x143, 0xc, 0xf, false);
  xb = __builtin_amdgcn_update_dpp(0, __float_as_int(b), 0x143, 0xc, 0xf, false);
  a += __int_as_float(xa); b += __int_as_float(xb);
  a = __int_as_float(__builtin_amdgcn_readlane(__float_as_int(a), 63));
  b = __int_as_float(__builtin_amdgcn_readlane(__float_as_int(b), 63));
}

// 8 interleaved full-wave sums; totals valid in lane 63.
template<int C,int RM,int BM,bool BC>
__device__ __forceinline__ void dpp_stage8(float m[8]){
  int x[8];
  #pragma unroll
  for (int j = 0; j < 8; ++j)
    x[j] = __builtin_amdgcn_update_dpp(0, __float_as_int(m[j]), C, RM, BM, BC);
  #pragma unroll
  for (int j = 0; j < 8; ++j) m[j] += __int_as_float(x[j]);
}
__device__ __forceinline__ void wave_total8_63(float m[8]){
  dpp_stage8<0x111,0xf,0xf,true>(m);
  dpp_stage8<0x112,0xf,0xf,true>(m);
  dpp_stage8<0x114,0xf,0xf,true>(m);
  dpp_stage8<0x118,0xf,0xf,true>(m);
  dpp_stage8<0x142,0xa,0xf,false>(m);
  dpp_stage8<0x143,0xc,0xf,false>(m);
}

// static-index accessor for a float4[9] record (avoids scratch; indices fold)
#define CCEL(A,i) ( ((i)&3)==0 ? (A)[(i)>>2].x : ((i)&3)==1 ? (A)[(i)>>2].y : \
                    ((i)&3)==2 ? (A)[(i)>>2].z : (A)[(i)>>2].w )

// ---------------- K0: pack ref bits + ref bytes -----
__global__ __launch_bounds__(64) void k_pack(const int* __restrict__ ref,
                                             uint64_t* __restrict__ pack,
                                             uint4* __restrict__ refB4){
  int g = blockIdx.x;
  int t = threadIdx.x;   // lane
  uint64_t wv = 0;
  for (int c = 0; c < 4; ++c){
    int i = g*4 + c;
    uint32_t m16 = 0;
    uint32_t d[4] = {0,0,0,0};
    #pragma unroll
    for (int j = 0; j < 16; ++j){
      int k = t*16 + j;
      uint32_t v = (k < NN) ? (uint32_t)(ref[(size_t)i*NN + k] & 1) : 0u;
      m16 |= v << j;
      d[j>>2] |= v << (8*(j&3));
    }
    wv |= (uint64_t)m16 << (16*c);
    refB4[(size_t)i*64 + t] = make_uint4(d[0],d[1],d[2],d[3]);
  }
  pack[(size_t)g*64 + t] = wv;
}

// ---------------- K0a: obs bit words (parallel) -----
__global__ __launch_bounds__(64) void k_obs(const float* __restrict__ xoh,
                                            uint32_t* __restrict__ obsw){
  int b2 = blockIdx.x;
  int w  = threadIdx.x;      // word index 0..63
  uint32_t word = 0;
  int base = w*32;
  #pragma unroll 4
  for (int z = 0; z < 32; ++z){
    int i = base + z;
    if (i < MM){
      float x1 = xoh[(size_t)b2*MM*2 + (size_t)i*2 + 1];
      if (x1 > 0.5f) word |= 1u << z;
    }
  }
  obsw[b2*64 + w] = word;
}

// ---------------- K0b: forward scalar table (c0,c1,1-rn,rn/n) -----
__global__ __launch_bounds__(256) void k_prep2(const float* __restrict__ xoh,
                                               const float* __restrict__ recomb,
                                               float4* __restrict__ FC4){
  int idx = blockIdx.x*256 + threadIdx.x;
  if (idx < NB2*MM){
    int b2 = idx / MM, i = idx - b2*MM;
    float x1 = xoh[(size_t)b2*MM*2 + (size_t)i*2 + 1];
    bool obs = x1 > 0.5f;
    float c0 = obs ? EBV : EAV;
    float c1 = obs ? (EAV-EBV) : (EBV-EAV);
    float rn = (i+1 < MM) ? recomb[i+1] : 0.5f;
    FC4[(size_t)b2*MM + i] = make_float4(c0, c1, 1.0f - rn, rn/(float)NN);
  }
}

// ---------------- K1: GEMM partial ----------------
__global__ __launch_bounds__(256) void k_gemm(const float* __restrict__ gexp,
                                              const float* __restrict__ W,
                                              float* __restrict__ part){
  int cb = blockIdx.x;        // 0..7 column block
  int c  = blockIdx.y;        // 0..15 d-chunk
  int t  = threadIdx.x;
  int d0 = (c*DDIM) >> 4, d1 = ((c+1)*DDIM) >> 4;
  int len = d1 - d0;          // 312 or 313
  __shared__ __align__(16) float lg[313*20];
  for (int bb = 0; bb < 16; ++bb)
    for (int dd = t; dd < len; dd += 256)
      lg[dd*20 + bb] = gexp[(size_t)bb*DDIM + d0 + dd];
  __syncthreads();
  int i = cb*256 + t;
  if (i < MM){
    float acc[16];
    #pragma unroll
    for (int bb = 0; bb < 16; ++bb) acc[bb] = 0.f;
    for (int dd = 0; dd < len; ++dd){
      float w = W[(size_t)(d0 + dd)*MM + i];
      const float4* lp = (const float4*)&lg[dd*20];
      float4 g0 = lp[0], g1 = lp[1], g2 = lp[2], g3 = lp[3];
      acc[0]  += g0.x*w; acc[1]  += g0.y*w; acc[2]  += g0.z*w; acc[3]  += g0.w*w;
      acc[4]  += g1.x*w; acc[5]  += g1.y*w; acc[6]  += g1.z*w; acc[7]  += g1.w*w;
      acc[8]  += g2.x*w; acc[9]  += g2.y*w; acc[10] += g2.z*w; acc[11] += g2.w*w;
      acc[12] += g3.x*w; acc[13] += g3.y*w; acc[14] += g3.z*w; acc[15] += g3.w*w;
    }
    #pragma unroll
    for (int bb = 0; bb < 16; ++bb)
      part[((size_t)c*16 + bb)*MM + i] = acc[bb];
  }
}

// ---------------- K2: reduce partials -> logits; backward scalar table -----
__global__ __launch_bounds__(256) void k_gemmreduce(const float* __restrict__ part,
                                                    const float* __restrict__ bias,
                                                    const float* __restrict__ recomb,
                                                    float* __restrict__ acc,
                                                    float4* __restrict__ BC4){
  int idx = blockIdx.x*256 + threadIdx.x;
  if (idx < 16*MM){
    float s = 0.f;
    #pragma unroll
    for (int c = 0; c < 16; ++c) s += part[(size_t)c*16*MM + idx];
    acc[idx] = s;
    int bb = idx / MM, i = idx - bb*MM;
    float z = s + bias[i];
    float p = rcp_fast(1.0f + __expf(-z));
    float v0 = EAV + (EBV-EAV)*p;
    float v1 = EBV + (EAV-EBV)*p;
    float r = recomb[i];
    BC4[idx] = make_float4(v0, v1 - v0, 1.0f - r, r/(float)NN);
  }
}

// ---------------- K2b: per-batch emission-product sums C_{l,j} ----------
__global__ __launch_bounds__(64) void k_ctab(const uint4* __restrict__ refB4,
                                             const float4* __restrict__ FC4,
                                             const float4* __restrict__ BC4,
                                             float* __restrict__ Cout){
  int wid  = blockIdx.x;           // 0 .. 64*NBAT-1
  int lane = threadIdx.x;
  int chain = wid / NBAT;
  int nb    = wid - chain*NBAT;
  int DIR = (chain < 32) ? 1 : -1;
  int b2  = chain & 31;
  const float4* ctab = (chain < 32) ? (FC4 + (size_t)b2*MM) : (BC4 + (size_t)(b2>>1)*MM);
  int start = (DIR > 0) ? 0 : (MM-1);

  // build e for the batch's 8 sites (16 states/lane)
  f32x2 e[8][8];
  #pragma unroll
  for (int m = 0; m < 8; ++m){
    int site = start + DIR*(nb*JB + m);
    uint4 by = refB4[(size_t)site*64 + lane];
    float4 cc = ctab[site];
    f32x2 c0p; c0p.x = cc.x; c0p.y = cc.x;
    f32x2 c1p; c1p.x = cc.y; c1p.y = cc.y;
    uint32_t rw[4] = {by.x, by.y, by.z, by.w};
    #pragma unroll
    for (int q = 0; q < 4; ++q){
      f32x2 b01, b23;
      b01.x = (float)( rw[q]        & 0xFFu);
      b01.y = (float)((rw[q] >> 8)  & 0xFFu);
      b23.x = (float)((rw[q] >> 16) & 0xFFu);
      b23.y = (float)( rw[q] >> 24);
      e[m][2*q]   = c0p + c1p*b01;
      e[m][2*q+1] = c0p + c1p*b23;
    }
  }
  const float mlo = (lane < 63) ? 1.0f : 0.0f;  // pairs 0..3 (states +0..7)
  const float mhi = (lane < 62) ? 1.0f : 0.0f;  // pairs 4..7 (states +8..15)

  __shared__ float red[64*NCR];
  int cnt = 0;
  #pragma unroll
  for (int l = 0; l < 8; ++l){
    f32x2 c[8];
    #pragma unroll
    for (int q = 0; q < 8; ++q){
      f32x2 mk; mk.x = (q < 4) ? mlo : mhi; mk.y = mk.x;
      c[q] = e[l][q] * mk;
    }
    #pragma unroll
    for (int jj = l; jj < 8; ++jj){
      if (jj > l){
        #pragma unroll
        for (int q = 0; q < 8; ++q) c[q] = c[q] * e[jj][q];
      }
      f32x2 s0 = (c[0]+c[1]) + (c[2]+c[3]);
      f32x2 s1 = (c[4]+c[5]) + (c[6]+c[7]);
      f32x2 ss = s0 + s1;
      red[lane*NCR + cnt] = ss.x + ss.y;
      ++cnt;
    }
  }
  __syncthreads();
  if (lane < NCR){
    float s = 0.f;
    #pragma unroll
    for (int k = 0; k < 64; ++k) s += red[k*NCR + lane];
    Cout[(size_t)wid*NCR + lane] = s;
  }
}

// ---------------- K3: sequential chains, batched exchange (J=8), 4 waves ------
// Round-7 changes (revert to 4 waves; shorten the serial chain):
//  - pre-barrier: D[l][j] = (prod_{m=l}^{j-1} az_m) * C[l][j], azp[j], and
//    SP[j] = d_entry * D[0][j] computed from az/CC only (parallel, hidden).
//  - post-barrier: S[j] = fma(azp[j], M[j], SP[j]); serial chain is just
//    R_j = S[j]; d_j = w_j*R_j; S[j2>j] += d_j*D[j+1][j2] (rank-1, parallel).
//    Critical path ~8 cy/site instead of ~40 (the old 8-term fmaf chain).
//  - D is COMPUTED (not loaded): register remat costs a re-mul, not a
//    120-cy LDS reload on the serial path (R3/R5 failure mode).
//  - M extraction via lane-indexed ds_read_b128 + v_readlane.
template<int DIR>
__device__ void run_chain4(const uint32_t* __restrict__ refW,
                           const float4* __restrict__ ctab,
                           const float* __restrict__ Crec,
                           uint16_t* __restrict__ outp,
                           int b2, int w, int lane,
                           float4* lds_ctab, float* lds_C, float* partb){
  int tid = w*64 + lane;
  for (int idx = tid; idx < MM; idx += 256) lds_ctab[idx] = ctab[idx];
  for (int idx = tid; idx < NBAT*NCR; idx += 256) lds_C[idx] = Crec[idx];
  __syncthreads();

  // states for this wave/lane: w*256 + lane*4 .. +3
  const float mv  = ((w < 3) || (lane < 58)) ? 1.0f : 0.0f;  // true states (<1000)
  const bool doSt = (w < 3) || (lane < 60);                  // states <1008 stored

  const ptrdiff_t rstep = (ptrdiff_t)DIR * 256;  // dwords per site
  const uint32_t* rp = refW + ((DIR > 0) ? 0 : (ptrdiff_t)(MM-1)*256) + tid;
  const ptrdiff_t ostep = (ptrdiff_t)DIR * NB2 * NPR;  // uint16 units per site
  uint16_t* op = outp + (size_t)b2*NPR
               + ((DIR > 0) ? (size_t)0 : (size_t)(MM-1)*(size_t)NB2*NPR)
               + (size_t)w*256 + (size_t)lane*4;

  uint32_t A[8], Bv[8];
  #pragma unroll
  for (int k = 0; k < 8; ++k) A[k]  = rp[(ptrdiff_t)k*rstep];
  #pragma unroll
  for (int k = 0; k < 8; ++k) Bv[k] = rp[(ptrdiff_t)(k+8)*rstep];

  int ci = (DIR > 0) ? 0 : (MM-1);

  float4 cur8[8];
  #pragma unroll
  for (int k = 0; k < 8; ++k) cur8[k] = lds_ctab[ci + DIR*k];

  f32x2 g0, g1;
  g0.x = 0.f; g0.y = 0.f; g1.x = 0.f; g1.y = 0.f;
  float dd      = 1.0f/(float)NN;  // d_{i0-1}
  float az_prev = 0.0f;            // az_{i0-1}
  int buf = 0;
  constexpr int CO[8] = {0,8,15,21,26,30,33,35};

  #pragma unroll 2
  for (int n = 0; n < NBAT; ++n){
    // ---- prefetch ref bytes two batches ahead (global; stays in flight) ----
    uint32_t Cv[8];
    #pragma unroll
    for (int k = 0; k < 8; ++k) Cv[k] = rp[(ptrdiff_t)(8*n + 16 + k)*rstep];
    // ---- prefetch next batch's per-site scalars (LDS; consumed next iter) ----
    float4 nx8[8];
    {
      int cin = (n < NBAT-1) ? (ci + DIR*8) : ci;
      #pragma unroll
      for (int k = 0; k < 8; ++k) nx8[k] = lds_ctab[cin + DIR*k];
    }
    // ---- this batch's C record (LDS; consumed pre-barrier in D compute) ----
    float4 CC[9];
    {
      const float4* crp = (const float4*)(lds_C + n*NCR);
      #pragma unroll
      for (int r = 0; r < 9; ++r) CC[r] = crp[r];
    }
    // ---- build e for the batch ----
    f32x2 e0[8], e1[8];
    #pragma unroll
    for (int k = 0; k < 8; ++k){
      uint32_t rw = A[k];
      f32x2 c0p; c0p.x = cur8[k].x; c0p.y = cur8[k].x;
      f32x2 c1p; c1p.x = cur8[k].y; c1p.y = cur8[k].y;
      f32x2 b01, b23;
      b01.x = (float)( rw        & 0xFFu);
      b01.y = (float)((rw >> 8)  & 0xFFu);
      b23.x = (float)((rw >> 16) & 0xFFu);
      b23.y = (float)( rw >> 24);
      e0[k] = c0p + c1p*b01;
      e1[k] = c0p + c1p*b23;
    }
    // ---- cumprod moments: m[j] = in-lane partial of g o e_0 o..o e_j ----
    float m[8];
    {
      f32x2 c0 = g0*e0[0], c1 = g1*e1[0];
      f32x2 hv = c0 + c1;
      m[0] = hv.x + hv.y;
      #pragma unroll
      for (int k = 1; k < 8; ++k){
        c0 = c0*e0[k]; c1 = c1*e1[k];
        f32x2 h = c0 + c1;
        m[k] = h.x + h.y;
      }
    }
    wave_total8_63(m);
    if (lane == 63){
      #pragma unroll
      for (int j = 0; j < 8; ++j) partb[buf*32 + j*4 + w] = m[j];
    }
    // ---- pre-barrier scalar prep (independent of M): azp, D, SP ----
    float azv[8], wv8[8];
    #pragma unroll
    for (int k = 0; k < 8; ++k){ azv[k] = cur8[k].z; wv8[k] = cur8[k].w; }
    float azp[8];
    azp[0] = az_prev;
    #pragma unroll
    for (int j = 1; j < 8; ++j) azp[j] = azp[j-1]*azv[j-1];
    float D[36];
    #pragma unroll
    for (int l = 0; l < 8; ++l){
      float pr = 1.0f;
      D[CO[l]] = CCEL(CC, CO[l]);
      #pragma unroll
      for (int j = l+1; j < 8; ++j){
        pr *= azv[j-1];
        D[CO[l] + (j-l)] = pr * CCEL(CC, CO[l] + (j-l));
      }
    }
    float SP[8];
    #pragma unroll
    for (int j = 0; j < 8; ++j) SP[j] = dd * D[j];   // l=0 row: D[0..7]
    barrier_lds_only();
    // ---- M via lane-indexed read + readlane ----
    float M[8];
    {
      int ll = lane & 7;
      const float4 pp = *(const float4*)(partb + buf*32 + ll*4);
      float msum = (pp.x + pp.y) + (pp.z + pp.w);
      #pragma unroll
      for (int j = 0; j < 8; ++j)
        M[j] = __int_as_float(__builtin_amdgcn_readlane(__float_as_int(msum), j));
    }
    // ---- short serial chain + rank-1 updates + fused elementwise ----
    float S[8];
    #pragma unroll
    for (int j = 0; j < 8; ++j) S[j] = fmaf(azp[j], M[j], SP[j]);
    float R = 1.0f;
    float dprev = dd;     // d_{j-1}, starts at d_entry
    #pragma unroll
    for (int j = 0; j < 8; ++j){
      R = S[j];
      float dj = wv8[j] * R;
      // elementwise for site j (uses az_{j-1}, d_{j-1}; independent of R_j)
      float az_j = (j == 0) ? az_prev : azv[j-1];
      float dm = dprev * mv;
      f32x2 azvp; azvp.x = az_j; azvp.y = az_j;
      f32x2 dmv;  dmv.x = dm;    dmv.y = dm;
      f32x2 t0 = g0*azvp + dmv;
      f32x2 t1 = g1*azvp + dmv;
      if (doSt){
        u32x2 v;
        v.x = __builtin_amdgcn_perm(__float_as_uint(t0.y), __float_as_uint(t0.x), 0x07060302u);
        v.y = __builtin_amdgcn_perm(__float_as_uint(t1.y), __float_as_uint(t1.x), 0x07060302u);
        *(u32x2*)op = v;
      }
      op += ostep;
      g0 = t0*e0[j];
      g1 = t1*e1[j];
      // rank-1 update of pending sums with d_j (row l=j+1)
      #pragma unroll
      for (int j2 = j+1; j2 < 8; ++j2)
        S[j2] = fmaf(dj, D[CO[j+1] + (j2-(j+1))], S[j2]);
      dprev = dj;
    }
    // ---- per-batch renorm (range only; scale cancels downstream) ----
    float s = rcp_fast(R);
    f32x2 sp; sp.x = s; sp.y = s;
    g0 = g0*sp; g1 = g1*sp;
    dd = dprev * s;
    az_prev = azv[7];
    ci += DIR*8;
    buf ^= 1;
    #pragma unroll
    for (int k = 0; k < 8; ++k){ A[k] = Bv[k]; Bv[k] = Cv[k]; }
    #pragma unroll
    for (int k = 0; k < 8; ++k) cur8[k] = nx8[k];
  }
}

__global__ __launch_bounds__(256, 1) void k_chains(const uint4* __restrict__ refB4,
                                                   const float4* __restrict__ FC4,
                                                   const float4* __restrict__ BC4,
                                                   const float* __restrict__ Cw,
                                                   uint16_t* __restrict__ F,
                                                   uint16_t* __restrict__ S){
  __shared__ __align__(16) float4 lds_ctab[MM];
  __shared__ __align__(16) float lds_C[NBAT*NCR];
  __shared__ __align__(16) float partb[64];   // [2 buf][8 j][4 w]
  int lane = threadIdx.x & 63;
  int w    = threadIdx.x >> 6;
  int blk  = blockIdx.x;
  int b2   = blk & 31;
  const uint32_t* refW = (const uint32_t*)refB4;
  const float* Crec = Cw + (size_t)blk*NBAT*NCR;
  if (blk < 32) run_chain4<1>(refW, FC4 + (size_t)b2*MM, Crec, F, b2, w, lane,
                              lds_ctab, lds_C, partb);
  else          run_chain4<-1>(refW, BC4 + (size_t)(b2>>1)*MM, Crec, S, b2, w, lane,
                               lds_ctab, lds_C, partb);
}

// ---------------- K4: per-site p_xe terms (fully parallel). wave per (i,b2). ----------
__global__ __launch_bounds__(256) void k_sites(const uint16_t* __restrict__ F,
                                               const uint16_t* __restrict__ S,
                                               const uint64_t* __restrict__ pack,
                                               const uint32_t* __restrict__ obsw,
                                               const float* __restrict__ acc,
                                               const float* __restrict__ bias,
                                               float* __restrict__ terms){
  int lane = threadIdx.x & 63;
  int wid  = threadIdx.x >> 6;
  int s    = blockIdx.x*4 + wid;     // 0 .. 63999
  int i    = s >> 5;
  int b2   = s & 31;
  uint4 f0 = make_uint4(0,0,0,0), f1 = f0, s0 = f0, s1 = f0;
  if (lane < 63){
    size_t off = ((size_t)i*NB2 + b2)*NPR + lane*16;
    const uint4* fp = (const uint4*)(F + off);
    const uint4* sp = (const uint4*)(S + off);
    f0 = fp[0]; f1 = fp[1];
    s0 = sp[0]; s1 = sp[1];
  }
  uint32_t m16 = (uint32_t)(pack[(size_t)(i>>2)*64 + lane] >> (16*(i&3))) & 0xFFFFu;

  uint32_t fa[8] = {f0.x,f0.y,f0.z,f0.w,f1.x,f1.y,f1.z,f1.w};
  uint32_t sa[8] = {s0.x,s0.y,s0.z,s0.w,s1.x,s1.y,s1.z,s1.w};
  float Tt = 0.f, Tb = 0.f;
  #pragma unroll
  for (int q = 0; q < 8; ++q){
    float flo = __uint_as_float(fa[q] << 16);
    float fhi = __uint_as_float(fa[q] & 0xFFFF0000u);
    float slo = __uint_as_float(sa[q] << 16);
    float shi = __uint_as_float(sa[q] & 0xFFFF0000u);
    float pl = flo*slo, ph = fhi*shi;
    Tt += pl + ph;
    Tb += (((m16 >> (2*q)) & 1u) ? pl : 0.f) + (((m16 >> (2*q+1)) & 1u) ? ph : 0.f);
  }
  wave_total2(Tt, Tb);
  if (lane == 0){
    uint32_t obsb = (obsw[b2*64 + (i>>5)] >> (i & 31)) & 1u;
    float z = acc[(size_t)(b2 >> 1)*MM + i] + bias[i];
    float p = rcp_fast(1.0f + __expf(-z));
    float A = Tt - Tb, B = Tb;
    float d0 = EAV*A + EBV*B;
    float d1 = EBV*A + EAV*B;
    float w0 = d0*(1.0f - p), w1 = d1*p;
    float term = __logf((obsb ? w1 : w0) * rcp_fast(w0 + w1));
    terms[s] = term;
  }
}

// ---------------- K5: final reduction ----------
__global__ __launch_bounds__(256) void k_final(const float* __restrict__ terms,
                                               float* __restrict__ out){
  __shared__ float red[256];
  float s = 0.f;
  for (int idx = threadIdx.x; idx < MM*NB2; idx += 256) s += terms[idx];
  red[threadIdx.x] = s;
  __syncthreads();
  for (int st = 128; st > 0; st >>= 1){
    if (threadIdx.x < st) red[threadIdx.x] += red[threadIdx.x + st];
    __syncthreads();
  }
  if (threadIdx.x == 0) out[0] = -red[0];
}

extern "C" void kernel_launch(void* const* d_in, const int* in_sizes, int n_in,
                              void* d_out, int out_size, void* d_ws, size_t ws_size,
                              hipStream_t stream){
  const float* gexp   = (const float*)d_in[0];   // [16,5000]
  const float* xoh    = (const float*)d_in[1];   // [32,2000,2]
  const float* W      = (const float*)d_in[2];   // [5000,2000]
  const float* bias   = (const float*)d_in[3];   // [2000]
  const int*   ref    = (const int*)d_in[4];     // [2000,1000]
  const float* recomb = (const float*)d_in[5];   // [2000]
  float* out = (float*)d_out;
  char* ws = (char*)d_ws;

  const size_t stateBytes = (size_t)MM*NB2*NPR*2;      // 129,024,000 per array (bf16)
  size_t offF    = 0;
  size_t offS    = offF + stateBytes;                  // 129,024,000
  size_t offPack = offS + stateBytes;                  // 258,048,000
  size_t offObs  = offPack + (size_t)NG*64*8;          // 258,304,000
  size_t offPart = offObs + 32*64*4;                   // 258,312,192 (2,048,000)
  size_t offTerm = offPart + (size_t)16*16*MM*4;       // 260,360,192 (256,000)
  size_t offAcc  = offTerm + (size_t)MM*NB2*4;         // 260,616,192 (128,000)
  size_t offRefB = offAcc + (size_t)16*MM*4;           // 260,744,192
  size_t offFC4  = offRefB + (size_t)(MM+32)*1024;     // 262,824,960
  size_t offBC4  = offFC4 + (size_t)NB2*MM*16;         // 263,848,960 (+512,000)

  uint16_t* Fb   = (uint16_t*)(ws + offF);
  uint16_t* Sb   = (uint16_t*)(ws + offS);
  uint64_t* pack = (uint64_t*)(ws + offPack);
  uint32_t* obsw = (uint32_t*)(ws + offObs);
  float*    part = (float*)(ws + offPart);
  float*    Cw   = (float*)(ws + offPart);             // aliases part+term
  float*    term = (float*)(ws + offTerm);
  float*    accp = (float*)(ws + offAcc);
  uint4*    refB = (uint4*)(ws + offRefB) + 16*64;     // site 0, pad +/-16 sites
  float4*   FC4  = (float4*)(ws + offFC4);
  float4*   BC4  = (float4*)(ws + offBC4);

  hipLaunchKernelGGL(k_pack, dim3(NG), dim3(64), 0, stream, ref, pack, refB);
  hipLaunchKernelGGL(k_obs, dim3(32), dim3(64), 0, stream, xoh, obsw);
  hipLaunchKernelGGL(k_prep2, dim3((NB2*MM+255)/256), dim3(256), 0, stream, xoh, recomb, FC4);
  hipLaunchKernelGGL(k_gemm, dim3(8,16), dim3(256), 0, stream, gexp, W, part);
  hipLaunchKernelGGL(k_gemmreduce, dim3(125), dim3(256), 0, stream, part, bias, recomb, accp, BC4);
  hipLaunchKernelGGL(k_ctab, dim3(64*NBAT), dim3(64), 0, stream, refB, FC4, BC4, Cw);
  hipLaunchKernelGGL(k_chains, dim3(64), dim3(256), 0, stream, refB, FC4, BC4, Cw, Fb, Sb);
  hipLaunchKernelGGL(k_sites, dim3(MM*NB2/4), dim3(256), 0, stream, Fb, Sb, pack, obsw, accp, bias, term);
  hipLaunchKernelGGL(k_final, dim3(1), dim3(256), 0, stream, term, out);
}